// Round 15
// baseline (531.283 us; speedup 1.0000x reference)
//
#include <hip/hip_runtime.h>
#include <hip/hip_bf16.h>
#include <math.h>

// MoE: T=8192 tokens, D=1024, E=8 experts, F=4096, top-2 routing.
// Pipeline: router -> count -> scan(tile map) -> scatter -> gather_cast(Xg)
//   -> transpose(w1) -> GEMM1(fast-gelu)->H -> transpose(w2) -> GEMM2->Y -> combine.
// R15 A/B: GEMM1 = counted-vmcnt double-buffered pipe (vmcnt(8) keeps next tile's
// loads in flight across raw barriers; stage into a slot only after the barrier
// proving all waves finished reading it). GEMM2 = R14-exact single-buffer control.
// Shared GEMM core: ni-outer MFMA (src0 const per inner run, R12 +23%), C^T packed
// epilogue, XOR-swizzled LDS, global_load_lds staging, 128x128, launch_bounds(256,4)
// (R14: 4 waves/SIMD, +9%), n-fastest + bijective XCD-chunked swizzle.

#define TK 8192
#define DDIM 1024
#define FDIM 4096
#define NEXP 8
#define MAXT128 136

typedef unsigned short u16;
typedef __attribute__((ext_vector_type(8))) short bf16x8;
typedef __attribute__((ext_vector_type(4))) float f32x4;

typedef const __attribute__((address_space(1))) unsigned int* gp_u32;
typedef __attribute__((address_space(3))) unsigned int* lp_u32;

__device__ __forceinline__ u16 f2bf(float f) {
  unsigned x = __float_as_uint(f);
  x += 0x7fffu + ((x >> 16) & 1u);
  return (u16)(x >> 16);
}

__device__ __forceinline__ float fast_gelu(float v) {
  // tanh-form GELU: v * sigmoid(1.5957691v + 0.0713548162v^3)
  float p = v * (1.5957691216f + 0.0713548162f * v * v);
  float t = __expf(p);
  return v * t * __builtin_amdgcn_rcpf(t + 1.0f);
}

__device__ __forceinline__ bf16x8 ldfrag(const char* base, int row, int slot) {
  return *(const bf16x8*)(base + row * 128 + ((slot ^ (row & 7)) << 4));
}

// ---------------- router: one wave per token ----------------
__global__ void router_kernel(const float* __restrict__ x, const float* __restrict__ gw,
                              const float* __restrict__ gb,
                              int* __restrict__ top_e, float* __restrict__ top_w) {
  const int t = blockIdx.x;
  const int l = threadIdx.x;  // 64
  const float* xr = x + (size_t)t * DDIM;
  float acc[8] = {0, 0, 0, 0, 0, 0, 0, 0};
  for (int k = l; k < DDIM; k += 64) {
    float xv = xr[k];
    const float4* g4 = (const float4*)(gw + (size_t)k * 8);
    float4 ga = g4[0], gbv = g4[1];
    acc[0] = fmaf(xv, ga.x, acc[0]);  acc[1] = fmaf(xv, ga.y, acc[1]);
    acc[2] = fmaf(xv, ga.z, acc[2]);  acc[3] = fmaf(xv, ga.w, acc[3]);
    acc[4] = fmaf(xv, gbv.x, acc[4]); acc[5] = fmaf(xv, gbv.y, acc[5]);
    acc[6] = fmaf(xv, gbv.z, acc[6]); acc[7] = fmaf(xv, gbv.w, acc[7]);
  }
#pragma unroll
  for (int e = 0; e < 8; ++e)
#pragma unroll
    for (int m = 32; m; m >>= 1) acc[e] += __shfl_xor(acc[e], m, 64);
  if (l == 0) {
    float lg[8];
#pragma unroll
    for (int e = 0; e < 8; ++e) lg[e] = acc[e] + gb[e];
    int i1 = 0;
#pragma unroll
    for (int e = 1; e < 8; ++e) if (lg[e] > lg[i1]) i1 = e;
    int i2 = (i1 == 0) ? 1 : 0;
#pragma unroll
    for (int e = 0; e < 8; ++e) if (e != i1 && lg[e] > lg[i2]) i2 = e;
    float e2 = __expf(lg[i2] - lg[i1]);
    float inv = 1.0f / (1.0f + e2);
    top_e[2 * t] = i1;      top_e[2 * t + 1] = i2;
    top_w[2 * t] = inv;     top_w[2 * t + 1] = e2 * inv;
  }
}

// ---------------- count ----------------
__global__ void count_kernel(const int* __restrict__ top_e, int* __restrict__ counts) {
  __shared__ int lc[8];
  if (threadIdx.x < 8) lc[threadIdx.x] = 0;
  __syncthreads();
  int t = blockIdx.x * 256 + threadIdx.x;
  if (t < TK) {
    atomicAdd(&lc[top_e[2 * t]], 1);
    atomicAdd(&lc[top_e[2 * t + 1]], 1);
  }
  __syncthreads();
  if (threadIdx.x < 8) atomicAdd(&counts[threadIdx.x], lc[threadIdx.x]);
}

// ---------------- scan + tile map (128-row granularity) ----------------
__global__ void scan_kernel(const int* __restrict__ counts, int* __restrict__ seg,
                            int* __restrict__ cur, int* __restrict__ nt128,
                            int* __restrict__ map128) {
  if (threadIdx.x == 0) {
    int s = 0, i128 = 0;
    for (int e = 0; e < 8; ++e) {
      seg[e] = s; cur[e] = s;
      int c = counts[e];
      for (int mt = 0; mt * 128 < c; ++mt) map128[i128++] = (e << 16) | mt;
      s += c;
    }
    seg[8] = s;
    *nt128 = i128;
  }
}

// ---------------- scatter (+ inverse map for combine) ----------------
__global__ void scatter_kernel(const int* __restrict__ top_e, const float* __restrict__ top_w,
                               int* __restrict__ cur, int* __restrict__ tok_ids,
                               float* __restrict__ tok_wt, int* __restrict__ inv) {
  __shared__ int lcnt[8];
  __shared__ int lbase[8];
  if (threadIdx.x < 8) lcnt[threadIdx.x] = 0;
  __syncthreads();
  int t = blockIdx.x * 256 + threadIdx.x;
  int e[2]; float wv[2]; int lpos[2];
  bool valid = t < TK;
  if (valid) {
#pragma unroll
    for (int j = 0; j < 2; ++j) {
      e[j] = top_e[2 * t + j];
      wv[j] = top_w[2 * t + j];
      lpos[j] = atomicAdd(&lcnt[e[j]], 1);
    }
  }
  __syncthreads();
  if (threadIdx.x < 8) lbase[threadIdx.x] = atomicAdd(&cur[threadIdx.x], lcnt[threadIdx.x]);
  __syncthreads();
  if (valid) {
#pragma unroll
    for (int j = 0; j < 2; ++j) {
      int slot = lbase[e[j]] + lpos[j];
      tok_ids[slot] = t;
      tok_wt[slot] = wv[j];
      inv[2 * t + j] = slot;
    }
  }
}

// ---------------- gather + cast: Xg[slot][k] = bf16(x[tok_ids[slot]][k]) ----------------
__global__ void gather_cast_kernel(const float* __restrict__ x, const int* __restrict__ tok_ids,
                                   uint4* __restrict__ Xg) {
  int idx = blockIdx.x * 256 + threadIdx.x;   // 2*TK*128 threads, 8 elems each
  int row = idx >> 7, c8 = (idx & 127) * 8;
  long tok = tok_ids[row];
  const float4* p = (const float4*)(x + tok * DDIM + c8);
  float4 a = p[0], b = p[1];
  uint4 o;
  o.x = (unsigned)f2bf(a.x) | ((unsigned)f2bf(a.y) << 16);
  o.y = (unsigned)f2bf(a.z) | ((unsigned)f2bf(a.w) << 16);
  o.z = (unsigned)f2bf(b.x) | ((unsigned)f2bf(b.y) << 16);
  o.w = (unsigned)f2bf(b.z) | ((unsigned)f2bf(b.w) << 16);
  Xg[idx] = o;
}

// ---------------- weight transpose + cast: [E][K][N] f32 -> [E][N][K] bf16 ----------------
__global__ void transpose_cast_kernel(const float* __restrict__ src, u16* __restrict__ dst,
                                      int K, int N) {
  __shared__ u16 tile[64][66];
  const int t = threadIdx.x;
  const float* s = src + (size_t)blockIdx.z * K * N + (size_t)(blockIdx.x * 64) * N + blockIdx.y * 64;
  u16* d = dst + (size_t)blockIdx.z * N * K + (size_t)(blockIdx.y * 64) * K + blockIdx.x * 64;
#pragma unroll
  for (int r = 0; r < 4; ++r) {
    int idx = r * 256 + t;
    int kk = idx >> 4, nn4 = (idx & 15) * 4;
    float4 v = *(const float4*)(s + (size_t)kk * N + nn4);
    tile[kk][nn4 + 0] = f2bf(v.x);
    tile[kk][nn4 + 1] = f2bf(v.y);
    tile[kk][nn4 + 2] = f2bf(v.z);
    tile[kk][nn4 + 3] = f2bf(v.w);
  }
  __syncthreads();
#pragma unroll
  for (int r = 0; r < 2; ++r) {
    int idx = r * 256 + t;
    int nn = idx >> 3, kk8 = (idx & 7) * 8;
    uint4 o;
    o.x = (unsigned)tile[kk8 + 0][nn] | ((unsigned)tile[kk8 + 1][nn] << 16);
    o.y = (unsigned)tile[kk8 + 2][nn] | ((unsigned)tile[kk8 + 3][nn] << 16);
    o.z = (unsigned)tile[kk8 + 4][nn] | ((unsigned)tile[kk8 + 5][nn] << 16);
    o.w = (unsigned)tile[kk8 + 6][nn] | ((unsigned)tile[kk8 + 7][nn] << 16);
    *(uint4*)(d + (size_t)nn * K + kk8) = o;
  }
}

// ---------------- GEMM1: counted-vmcnt double-buffered pipe ----------------
// Race-checked: (a) per-wave vmcnt(8) drains exactly tile kt (FIFO: kt,kt+1
// outstanding = 16); barrier AFTER vmcnt -> all waves' chunks landed.
// (b) second barrier after MFMA (+lgkm drain) proves all waves done reading
// buf[kt&1] before STAGE overwrites it with tile kt+2; those loads then have a
// full compute step of cover before their own vmcnt.
template <int PHASE, int BM, int BN, int CHA, int CHB>
__global__ __launch_bounds__(256, 4) void moe_gemm_pipe(
    const u16* __restrict__ A, const u16* __restrict__ Bt,
    const float* __restrict__ bias, u16* __restrict__ Hout,
    u16* __restrict__ Yout,
    const int* __restrict__ seg_off, const int* __restrict__ counts,
    const int* __restrict__ ntiles, const int* __restrict__ tile_map,
    int K, int N) {
  constexpr int MF = BM / 32;
  constexpr int NF = BN / 32;

  const int NTm = *ntiles;
  const int nb = N / BN;
  const int nwg = NTm * nb;
  const int bid = (int)blockIdx.x;
  if (bid >= nwg) return;
  const int q = nwg >> 3, rr = nwg & 7;
  const int xcd = bid & 7, pos = bid >> 3;
  const int work = xcd * q + (xcd < rr ? xcd : rr) + pos;
  const int mtIdx = work / nb;
  const int n0 = (work % nb) * BN;

  const int ent = tile_map[mtIdx];
  const int e = ent >> 16;
  const int mt = ent & 0xffff;
  const int cnt = counts[e];
  const int seg = seg_off[e];

  const int t = threadIdx.x;
  const int w = t >> 6;
  const int l = t & 63;
  const int lr = l & 15, lh = l >> 4;
  const int wr = w >> 1, wc = w & 1;

  __shared__ u16 As[2][BM * 64];
  __shared__ u16 Bs[2][BN * 64];

  const u16* aga[CHA];
  const u16* bga[CHB];
  const u16* Bte = Bt + (size_t)e * N * K;
#pragma unroll
  for (int j = 0; j < CHA; ++j) {
    int c = t + 256 * j;
    int row = c >> 3;
    int js = (c & 7) ^ (row & 7);
    int m = mt * BM + row;
    if (m >= cnt) m = cnt - 1;
    aga[j] = A + (size_t)(seg + m) * K + js * 8;
  }
#pragma unroll
  for (int j = 0; j < CHB; ++j) {
    int c = t + 256 * j;
    int row = c >> 3;
    int js = (c & 7) ^ (row & 7);
    bga[j] = Bte + (size_t)(n0 + row) * K + js * 8;
  }

  auto STAGE = [&](int buf, int kt) {
#pragma unroll
    for (int j = 0; j < CHA; ++j)
      __builtin_amdgcn_global_load_lds((gp_u32)(aga[j] + (size_t)kt * 64),
                                       (lp_u32)(&As[buf][(t + 256 * j) * 8]), 16, 0, 0);
#pragma unroll
    for (int j = 0; j < CHB; ++j)
      __builtin_amdgcn_global_load_lds((gp_u32)(bga[j] + (size_t)kt * 64),
                                       (lp_u32)(&Bs[buf][(t + 256 * j) * 8]), 16, 0, 0);
  };

  f32x4 acc[MF][NF];
#pragma unroll
  for (int i = 0; i < MF; ++i)
#pragma unroll
    for (int j = 0; j < NF; ++j) acc[i][j] = (f32x4){0.f, 0.f, 0.f, 0.f};

  const int NT = K / 64;
  STAGE(0, 0);
  STAGE(1, 1);

  for (int kt = 0; kt < NT; ++kt) {
    if (kt + 1 < NT)
      asm volatile("s_waitcnt vmcnt(8)" ::: "memory");   // tile kt landed; kt+1 in flight
    else
      asm volatile("s_waitcnt vmcnt(0)" ::: "memory");
    __builtin_amdgcn_s_barrier();

    const char* AsB = (const char*)&As[kt & 1][0];
    const char* BsB = (const char*)&Bs[kt & 1][0];
#pragma unroll
    for (int kk = 0; kk < 2; ++kk) {
      const int slot = kk * 4 + lh;
      bf16x8 a[MF], b[NF];
#pragma unroll
      for (int mi = 0; mi < MF; ++mi)
        a[mi] = ldfrag(AsB, wr * (BM / 2) + mi * 16 + lr, slot);
#pragma unroll
      for (int ni = 0; ni < NF; ++ni)
        b[ni] = ldfrag(BsB, wc * (BN / 2) + ni * 16 + lr, slot);
#pragma unroll
      for (int ni = 0; ni < NF; ++ni)
#pragma unroll
        for (int mi = 0; mi < MF; ++mi)
          acc[mi][ni] = __builtin_amdgcn_mfma_f32_16x16x32_bf16(b[ni], a[mi], acc[mi][ni], 0, 0, 0);
    }
    asm volatile("s_waitcnt lgkmcnt(0)" ::: "memory");
    __builtin_amdgcn_s_barrier();
    if (kt + 2 < NT) STAGE(kt & 1, kt + 2);   // slot fully read by all waves
  }

  const float* be = bias + (size_t)e * N;
  u16* dst = (PHASE == 1) ? Hout : Yout;
#pragma unroll
  for (int mi = 0; mi < MF; ++mi) {
    int m = mt * BM + wr * (BM / 2) + mi * 16 + lr;
    if (m < cnt) {
      size_t orow = (size_t)(seg + m) * N;
#pragma unroll
      for (int ni = 0; ni < NF; ++ni) {
        int col = n0 + wc * (BN / 2) + ni * 16 + lh * 4;
        float4 bv = *(const float4*)(be + col);
        float v0 = acc[mi][ni][0] + bv.x;
        float v1 = acc[mi][ni][1] + bv.y;
        float v2 = acc[mi][ni][2] + bv.z;
        float v3 = acc[mi][ni][3] + bv.w;
        if (PHASE == 1) {
          v0 = fast_gelu(v0); v1 = fast_gelu(v1);
          v2 = fast_gelu(v2); v3 = fast_gelu(v3);
        }
        uint2 o;
        o.x = (unsigned)f2bf(v0) | ((unsigned)f2bf(v1) << 16);
        o.y = (unsigned)f2bf(v2) | ((unsigned)f2bf(v3) << 16);
        *(uint2*)(dst + orow + col) = o;
      }
    }
  }
}

// ---------------- GEMM2 control: R14-exact single-buffer loop ----------------
template <int PHASE, int BM, int BN, int CHA, int CHB>
__global__ __launch_bounds__(256, 4) void moe_gemm(
    const u16* __restrict__ A, const u16* __restrict__ Bt,
    const float* __restrict__ bias, u16* __restrict__ Hout,
    u16* __restrict__ Yout,
    const int* __restrict__ seg_off, const int* __restrict__ counts,
    const int* __restrict__ ntiles, const int* __restrict__ tile_map,
    int K, int N) {
  constexpr int MF = BM / 32;
  constexpr int NF = BN / 32;

  const int NTm = *ntiles;
  const int nb = N / BN;
  const int nwg = NTm * nb;
  const int bid = (int)blockIdx.x;
  if (bid >= nwg) return;
  const int q = nwg >> 3, rr = nwg & 7;
  const int xcd = bid & 7, pos = bid >> 3;
  const int work = xcd * q + (xcd < rr ? xcd : rr) + pos;
  const int mtIdx = work / nb;
  const int n0 = (work % nb) * BN;

  const int ent = tile_map[mtIdx];
  const int e = ent >> 16;
  const int mt = ent & 0xffff;
  const int cnt = counts[e];
  const int seg = seg_off[e];

  const int t = threadIdx.x;
  const int w = t >> 6;
  const int l = t & 63;
  const int lr = l & 15, lh = l >> 4;
  const int wr = w >> 1, wc = w & 1;

  __shared__ u16 As[BM * 64];
  __shared__ u16 Bs[BN * 64];

  const u16* aga[CHA];
  const u16* bga[CHB];
  const u16* Bte = Bt + (size_t)e * N * K;
#pragma unroll
  for (int j = 0; j < CHA; ++j) {
    int c = t + 256 * j;
    int row = c >> 3;
    int js = (c & 7) ^ (row & 7);
    int m = mt * BM + row;
    if (m >= cnt) m = cnt - 1;
    aga[j] = A + (size_t)(seg + m) * K + js * 8;
  }
#pragma unroll
  for (int j = 0; j < CHB; ++j) {
    int c = t + 256 * j;
    int row = c >> 3;
    int js = (c & 7) ^ (row & 7);
    bga[j] = Bte + (size_t)(n0 + row) * K + js * 8;
  }

  f32x4 acc[MF][NF];
#pragma unroll
  for (int i = 0; i < MF; ++i)
#pragma unroll
    for (int j = 0; j < NF; ++j) acc[i][j] = (f32x4){0.f, 0.f, 0.f, 0.f};

  const int NT = K / 64;
  for (int kt = 0; kt < NT; ++kt) {
#pragma unroll
    for (int j = 0; j < CHA; ++j)
      __builtin_amdgcn_global_load_lds((gp_u32)(aga[j] + (size_t)kt * 64),
                                       (lp_u32)(&As[(t + 256 * j) * 8]), 16, 0, 0);
#pragma unroll
    for (int j = 0; j < CHB; ++j)
      __builtin_amdgcn_global_load_lds((gp_u32)(bga[j] + (size_t)kt * 64),
                                       (lp_u32)(&Bs[(t + 256 * j) * 8]), 16, 0, 0);
    __syncthreads();

    const char* AsB = (const char*)As;
    const char* BsB = (const char*)Bs;
#pragma unroll
    for (int kk = 0; kk < 2; ++kk) {
      const int slot = kk * 4 + lh;
      bf16x8 a[MF], b[NF];
#pragma unroll
      for (int mi = 0; mi < MF; ++mi)
        a[mi] = ldfrag(AsB, wr * (BM / 2) + mi * 16 + lr, slot);
#pragma unroll
      for (int ni = 0; ni < NF; ++ni)
        b[ni] = ldfrag(BsB, wc * (BN / 2) + ni * 16 + lr, slot);
#pragma unroll
      for (int ni = 0; ni < NF; ++ni)
#pragma unroll
        for (int mi = 0; mi < MF; ++mi)
          acc[mi][ni] = __builtin_amdgcn_mfma_f32_16x16x32_bf16(b[ni], a[mi], acc[mi][ni], 0, 0, 0);
    }
    __syncthreads();
  }

  const float* be = bias + (size_t)e * N;
  u16* dst = (PHASE == 1) ? Hout : Yout;
#pragma unroll
  for (int mi = 0; mi < MF; ++mi) {
    int m = mt * BM + wr * (BM / 2) + mi * 16 + lr;
    if (m < cnt) {
      size_t orow = (size_t)(seg + m) * N;
#pragma unroll
      for (int ni = 0; ni < NF; ++ni) {
        int col = n0 + wc * (BN / 2) + ni * 16 + lh * 4;
        float4 bv = *(const float4*)(be + col);
        float v0 = acc[mi][ni][0] + bv.x;
        float v1 = acc[mi][ni][1] + bv.y;
        float v2 = acc[mi][ni][2] + bv.z;
        float v3 = acc[mi][ni][3] + bv.w;
        if (PHASE == 1) {
          v0 = fast_gelu(v0); v1 = fast_gelu(v1);
          v2 = fast_gelu(v2); v3 = fast_gelu(v3);
        }
        uint2 o;
        o.x = (unsigned)f2bf(v0) | ((unsigned)f2bf(v1) << 16);
        o.y = (unsigned)f2bf(v2) | ((unsigned)f2bf(v3) << 16);
        *(uint2*)(dst + orow + col) = o;
      }
    }
  }
}

// ---------------- combine: out[t] = w0*Y[inv0] + w1*Y[inv1] ----------------
__global__ void combine_kernel(const u16* __restrict__ Y, const int* __restrict__ inv,
                               const float* __restrict__ top_w, float* __restrict__ out) {
  int idx = blockIdx.x * 256 + threadIdx.x;   // TK*128 threads, 8 cols each
  int t = idx >> 7, c = (idx & 127) * 8;
  int s0 = inv[2 * t], s1 = inv[2 * t + 1];
  float w0 = top_w[2 * t], w1 = top_w[2 * t + 1];
  const uint4 y0 = *(const uint4*)(Y + (size_t)s0 * DDIM + c);
  const uint4 y1 = *(const uint4*)(Y + (size_t)s1 * DDIM + c);
  float4 o0, o1;
#define LO(u) __uint_as_float((u) << 16)
#define HI(u) __uint_as_float((u) & 0xffff0000u)
  o0.x = w0 * LO(y0.x) + w1 * LO(y1.x); o0.y = w0 * HI(y0.x) + w1 * HI(y1.x);
  o0.z = w0 * LO(y0.y) + w1 * LO(y1.y); o0.w = w0 * HI(y0.y) + w1 * HI(y1.y);
  o1.x = w0 * LO(y0.z) + w1 * LO(y1.z); o1.y = w0 * HI(y0.z) + w1 * HI(y1.z);
  o1.z = w0 * LO(y0.w) + w1 * LO(y1.w); o1.w = w0 * HI(y0.w) + w1 * HI(y1.w);
#undef LO
#undef HI
  float4* op = (float4*)(out + (size_t)t * DDIM + c);
  op[0] = o0; op[1] = o1;
}

extern "C" void kernel_launch(void* const* d_in, const int* in_sizes, int n_in,
                              void* d_out, int out_size, void* d_ws, size_t ws_size,
                              hipStream_t stream) {
  const float* x  = (const float*)d_in[0];
  const float* gw = (const float*)d_in[1];
  const float* gb = (const float*)d_in[2];
  const float* w1 = (const float*)d_in[3];
  const float* b1 = (const float*)d_in[4];
  const float* w2 = (const float*)d_in[5];
  const float* b2 = (const float*)d_in[6];
  float* out = (float*)d_out;

  char* ws = (char*)d_ws;
  int*   counts  = (int*)(ws + 0);
  int*   cursors = (int*)(ws + 64);
  int*   seg     = (int*)(ws + 128);
  int*   nt128   = (int*)(ws + 192);
  int*   map128  = (int*)(ws + 1024);
  int*   top_e   = (int*)(ws + 4096);
  float* top_w   = (float*)(ws + 4096 + 65536);
  int*   tok_ids = (int*)(ws + 4096 + 131072);
  float* tok_wt  = (float*)(ws + 4096 + 196608);
  int*   invm    = (int*)(ws + 4096 + 262144);
  // Xg and Y share [1MB, 36MB): Xg consumed by GEMM1, Y produced by GEMM2.
  u16*   Xg      = (u16*)(ws + ((size_t)1 << 20));    //  32 MB
  u16*   Y       = (u16*)(ws + ((size_t)1 << 20));    //  33.6 MB (same region)
  u16*   H       = (u16*)(ws + ((size_t)36 << 20));   // 128 MB
  u16*   wt      = (u16*)(ws + ((size_t)164 << 20));  //  64 MB (shared w1t/w2t)

  hipMemsetAsync(ws, 0, 256, stream);

  router_kernel<<<TK, 64, 0, stream>>>(x, gw, gb, top_e, top_w);
  count_kernel<<<TK / 256, 256, 0, stream>>>(top_e, counts);
  scan_kernel<<<1, 64, 0, stream>>>(counts, seg, cursors, nt128, map128);
  scatter_kernel<<<TK / 256, 256, 0, stream>>>(top_e, top_w, cursors, tok_ids, tok_wt, invm);
  gather_cast_kernel<<<2 * TK * 128 / 256, 256, 0, stream>>>(x, tok_ids, (uint4*)Xg);

  transpose_cast_kernel<<<dim3(DDIM / 64, FDIM / 64, NEXP), 256, 0, stream>>>(w1, wt, DDIM, FDIM);
  moe_gemm_pipe<1, 128, 128, 4, 4><<<dim3(MAXT128 * (FDIM / 128)), 256, 0, stream>>>(
      Xg, wt, b1, H, nullptr, seg, counts, nt128, map128, DDIM, FDIM);
  transpose_cast_kernel<<<dim3(FDIM / 64, DDIM / 64, NEXP), 256, 0, stream>>>(w2, wt, FDIM, DDIM);

  moe_gemm<3, 128, 128, 4, 4><<<dim3(MAXT128 * (DDIM / 128)), 256, 0, stream>>>(
      H, wt, b2, nullptr, Y, seg, counts, nt128, map128, FDIM, DDIM);
  combine_kernel<<<TK * 128 / 256, 256, 0, stream>>>(Y, invm, top_w, out);
}

// Round 16
// 480.901 us; speedup vs baseline: 1.1048x; 1.1048x over previous
//
#include <hip/hip_runtime.h>
#include <hip/hip_bf16.h>
#include <math.h>

// MoE: T=8192 tokens, D=1024, E=8 experts, F=4096, top-2 routing.
// Pipeline: router -> count -> scan(tile map) -> scatter -> gather_cast(Xg)
//   -> transpose(w1) -> GEMM1(fast-gelu)->H -> transpose(w2) -> GEMM2->Y -> combine.
// FINAL (R16 = R14-exact, measured best 481us): m97 single-buffer
// two-__syncthreads K-loop; ni-outer MFMA cluster (src0 const per inner run,
// R11->R12 +23%); C^T packed epilogue (swapped-operand mfma(b,a)) with uint2
// stores + float4 bias loads (R9->R10 VALU 49->26); XOR-swizzled LDS (0 bank
// conflicts); global_load_lds width-16 staging; launch_bounds(256,4) -> VGPR 60,
// 4 waves/SIMD (R14 +9%); n-fastest + bijective XCD-chunked swizzle (R8 killed
// 8x H over-fetch). Pipelining attempts (dbuf drain R10, counted-vmcnt R15)
// both lost to occupancy — wave-level co-scheduling at 4 blocks/CU already
// hides staging latency on this shape.

#define TK 8192
#define DDIM 1024
#define FDIM 4096
#define NEXP 8
#define MAXT128 136

typedef unsigned short u16;
typedef __attribute__((ext_vector_type(8))) short bf16x8;
typedef __attribute__((ext_vector_type(4))) float f32x4;

typedef const __attribute__((address_space(1))) unsigned int* gp_u32;
typedef __attribute__((address_space(3))) unsigned int* lp_u32;

__device__ __forceinline__ u16 f2bf(float f) {
  unsigned x = __float_as_uint(f);
  x += 0x7fffu + ((x >> 16) & 1u);
  return (u16)(x >> 16);
}

__device__ __forceinline__ float fast_gelu(float v) {
  // tanh-form GELU: v * sigmoid(1.5957691v + 0.0713548162v^3)
  float p = v * (1.5957691216f + 0.0713548162f * v * v);
  float t = __expf(p);
  return v * t * __builtin_amdgcn_rcpf(t + 1.0f);
}

__device__ __forceinline__ bf16x8 ldfrag(const char* base, int row, int slot) {
  return *(const bf16x8*)(base + row * 128 + ((slot ^ (row & 7)) << 4));
}

// ---------------- router: one wave per token ----------------
__global__ void router_kernel(const float* __restrict__ x, const float* __restrict__ gw,
                              const float* __restrict__ gb,
                              int* __restrict__ top_e, float* __restrict__ top_w) {
  const int t = blockIdx.x;
  const int l = threadIdx.x;  // 64
  const float* xr = x + (size_t)t * DDIM;
  float acc[8] = {0, 0, 0, 0, 0, 0, 0, 0};
  for (int k = l; k < DDIM; k += 64) {
    float xv = xr[k];
    const float4* g4 = (const float4*)(gw + (size_t)k * 8);
    float4 ga = g4[0], gbv = g4[1];
    acc[0] = fmaf(xv, ga.x, acc[0]);  acc[1] = fmaf(xv, ga.y, acc[1]);
    acc[2] = fmaf(xv, ga.z, acc[2]);  acc[3] = fmaf(xv, ga.w, acc[3]);
    acc[4] = fmaf(xv, gbv.x, acc[4]); acc[5] = fmaf(xv, gbv.y, acc[5]);
    acc[6] = fmaf(xv, gbv.z, acc[6]); acc[7] = fmaf(xv, gbv.w, acc[7]);
  }
#pragma unroll
  for (int e = 0; e < 8; ++e)
#pragma unroll
    for (int m = 32; m; m >>= 1) acc[e] += __shfl_xor(acc[e], m, 64);
  if (l == 0) {
    float lg[8];
#pragma unroll
    for (int e = 0; e < 8; ++e) lg[e] = acc[e] + gb[e];
    int i1 = 0;
#pragma unroll
    for (int e = 1; e < 8; ++e) if (lg[e] > lg[i1]) i1 = e;
    int i2 = (i1 == 0) ? 1 : 0;
#pragma unroll
    for (int e = 0; e < 8; ++e) if (e != i1 && lg[e] > lg[i2]) i2 = e;
    float e2 = __expf(lg[i2] - lg[i1]);
    float inv = 1.0f / (1.0f + e2);
    top_e[2 * t] = i1;      top_e[2 * t + 1] = i2;
    top_w[2 * t] = inv;     top_w[2 * t + 1] = e2 * inv;
  }
}

// ---------------- count ----------------
__global__ void count_kernel(const int* __restrict__ top_e, int* __restrict__ counts) {
  __shared__ int lc[8];
  if (threadIdx.x < 8) lc[threadIdx.x] = 0;
  __syncthreads();
  int t = blockIdx.x * 256 + threadIdx.x;
  if (t < TK) {
    atomicAdd(&lc[top_e[2 * t]], 1);
    atomicAdd(&lc[top_e[2 * t + 1]], 1);
  }
  __syncthreads();
  if (threadIdx.x < 8) atomicAdd(&counts[threadIdx.x], lc[threadIdx.x]);
}

// ---------------- scan + tile map (128-row granularity) ----------------
__global__ void scan_kernel(const int* __restrict__ counts, int* __restrict__ seg,
                            int* __restrict__ cur, int* __restrict__ nt128,
                            int* __restrict__ map128) {
  if (threadIdx.x == 0) {
    int s = 0, i128 = 0;
    for (int e = 0; e < 8; ++e) {
      seg[e] = s; cur[e] = s;
      int c = counts[e];
      for (int mt = 0; mt * 128 < c; ++mt) map128[i128++] = (e << 16) | mt;
      s += c;
    }
    seg[8] = s;
    *nt128 = i128;
  }
}

// ---------------- scatter (+ inverse map for combine) ----------------
__global__ void scatter_kernel(const int* __restrict__ top_e, const float* __restrict__ top_w,
                               int* __restrict__ cur, int* __restrict__ tok_ids,
                               float* __restrict__ tok_wt, int* __restrict__ inv) {
  __shared__ int lcnt[8];
  __shared__ int lbase[8];
  if (threadIdx.x < 8) lcnt[threadIdx.x] = 0;
  __syncthreads();
  int t = blockIdx.x * 256 + threadIdx.x;
  int e[2]; float wv[2]; int lpos[2];
  bool valid = t < TK;
  if (valid) {
#pragma unroll
    for (int j = 0; j < 2; ++j) {
      e[j] = top_e[2 * t + j];
      wv[j] = top_w[2 * t + j];
      lpos[j] = atomicAdd(&lcnt[e[j]], 1);
    }
  }
  __syncthreads();
  if (threadIdx.x < 8) lbase[threadIdx.x] = atomicAdd(&cur[threadIdx.x], lcnt[threadIdx.x]);
  __syncthreads();
  if (valid) {
#pragma unroll
    for (int j = 0; j < 2; ++j) {
      int slot = lbase[e[j]] + lpos[j];
      tok_ids[slot] = t;
      tok_wt[slot] = wv[j];
      inv[2 * t + j] = slot;
    }
  }
}

// ---------------- gather + cast: Xg[slot][k] = bf16(x[tok_ids[slot]][k]) ----------------
__global__ void gather_cast_kernel(const float* __restrict__ x, const int* __restrict__ tok_ids,
                                   uint4* __restrict__ Xg) {
  int idx = blockIdx.x * 256 + threadIdx.x;   // 2*TK*128 threads, 8 elems each
  int row = idx >> 7, c8 = (idx & 127) * 8;
  long tok = tok_ids[row];
  const float4* p = (const float4*)(x + tok * DDIM + c8);
  float4 a = p[0], b = p[1];
  uint4 o;
  o.x = (unsigned)f2bf(a.x) | ((unsigned)f2bf(a.y) << 16);
  o.y = (unsigned)f2bf(a.z) | ((unsigned)f2bf(a.w) << 16);
  o.z = (unsigned)f2bf(b.x) | ((unsigned)f2bf(b.y) << 16);
  o.w = (unsigned)f2bf(b.z) | ((unsigned)f2bf(b.w) << 16);
  Xg[idx] = o;
}

// ---------------- weight transpose + cast: [E][K][N] f32 -> [E][N][K] bf16 ----------------
// float4 loads, bf16 LDS tile (66-u16 row stride -> <=2-way bank aliasing),
// packed uint4 stores (2 per thread vs 16 scalar u16).
__global__ void transpose_cast_kernel(const float* __restrict__ src, u16* __restrict__ dst,
                                      int K, int N) {
  __shared__ u16 tile[64][66];
  const int t = threadIdx.x;
  const float* s = src + (size_t)blockIdx.z * K * N + (size_t)(blockIdx.x * 64) * N + blockIdx.y * 64;
  u16* d = dst + (size_t)blockIdx.z * N * K + (size_t)(blockIdx.y * 64) * K + blockIdx.x * 64;
#pragma unroll
  for (int r = 0; r < 4; ++r) {
    int idx = r * 256 + t;
    int kk = idx >> 4, nn4 = (idx & 15) * 4;
    float4 v = *(const float4*)(s + (size_t)kk * N + nn4);
    tile[kk][nn4 + 0] = f2bf(v.x);
    tile[kk][nn4 + 1] = f2bf(v.y);
    tile[kk][nn4 + 2] = f2bf(v.z);
    tile[kk][nn4 + 3] = f2bf(v.w);
  }
  __syncthreads();
#pragma unroll
  for (int r = 0; r < 2; ++r) {
    int idx = r * 256 + t;
    int nn = idx >> 3, kk8 = (idx & 7) * 8;
    uint4 o;
    o.x = (unsigned)tile[kk8 + 0][nn] | ((unsigned)tile[kk8 + 1][nn] << 16);
    o.y = (unsigned)tile[kk8 + 2][nn] | ((unsigned)tile[kk8 + 3][nn] << 16);
    o.z = (unsigned)tile[kk8 + 4][nn] | ((unsigned)tile[kk8 + 5][nn] << 16);
    o.w = (unsigned)tile[kk8 + 6][nn] | ((unsigned)tile[kk8 + 7][nn] << 16);
    *(uint4*)(d + (size_t)nn * K + kk8) = o;
  }
}

// ---------------- grouped GEMM, m97 single-buffer loop + C^T packed epilogue ----------------
// PHASE 1: H[slot][n] = bf16(fast_gelu(acc + b1[n]))
// PHASE 3: Y[slot][n] = bf16(acc + b2[n])
template <int PHASE, int BM, int BN, int CHA, int CHB>
__global__ __launch_bounds__(256, 4) void moe_gemm(
    const u16* __restrict__ A, const u16* __restrict__ Bt,
    const float* __restrict__ bias, u16* __restrict__ Hout,
    u16* __restrict__ Yout,
    const int* __restrict__ seg_off, const int* __restrict__ counts,
    const int* __restrict__ ntiles, const int* __restrict__ tile_map,
    int K, int N) {
  constexpr int MF = BM / 32;   // m-frags per wave (2x2 wave grid)
  constexpr int NF = BN / 32;   // n-frags per wave

  const int NTm = *ntiles;
  const int nb = N / BN;
  const int nwg = NTm * nb;
  const int bid = (int)blockIdx.x;
  if (bid >= nwg) return;
  // bijective XCD-chunked swizzle (m204)
  const int q = nwg >> 3, rr = nwg & 7;
  const int xcd = bid & 7, pos = bid >> 3;
  const int work = xcd * q + (xcd < rr ? xcd : rr) + pos;
  const int mtIdx = work / nb;            // n fastest within XCD chunk
  const int n0 = (work % nb) * BN;

  const int ent = tile_map[mtIdx];
  const int e = ent >> 16;
  const int mt = ent & 0xffff;
  const int cnt = counts[e];
  const int seg = seg_off[e];

  const int t = threadIdx.x;
  const int w = t >> 6;
  const int l = t & 63;
  const int lr = l & 15, lh = l >> 4;
  const int wr = w >> 1, wc = w & 1;

  __shared__ u16 As[BM * 64];
  __shared__ u16 Bs[BN * 64];

  const u16* aga[CHA];
  const u16* bga[CHB];
  const u16* Bte = Bt + (size_t)e * N * K;
#pragma unroll
  for (int j = 0; j < CHA; ++j) {
    int c = t + 256 * j;
    int row = c >> 3;
    int js = (c & 7) ^ (row & 7);
    int m = mt * BM + row;
    if (m >= cnt) m = cnt - 1;
    aga[j] = A + (size_t)(seg + m) * K + js * 8;
  }
#pragma unroll
  for (int j = 0; j < CHB; ++j) {
    int c = t + 256 * j;
    int row = c >> 3;
    int js = (c & 7) ^ (row & 7);
    bga[j] = Bte + (size_t)(n0 + row) * K + js * 8;
  }

  f32x4 acc[MF][NF];
#pragma unroll
  for (int i = 0; i < MF; ++i)
#pragma unroll
    for (int j = 0; j < NF; ++j) acc[i][j] = (f32x4){0.f, 0.f, 0.f, 0.f};

  const int NT = K / 64;
  for (int kt = 0; kt < NT; ++kt) {
#pragma unroll
    for (int j = 0; j < CHA; ++j)
      __builtin_amdgcn_global_load_lds((gp_u32)(aga[j] + (size_t)kt * 64),
                                       (lp_u32)(&As[(t + 256 * j) * 8]), 16, 0, 0);
#pragma unroll
    for (int j = 0; j < CHB; ++j)
      __builtin_amdgcn_global_load_lds((gp_u32)(bga[j] + (size_t)kt * 64),
                                       (lp_u32)(&Bs[(t + 256 * j) * 8]), 16, 0, 0);
    __syncthreads();

    const char* AsB = (const char*)As;
    const char* BsB = (const char*)Bs;
#pragma unroll
    for (int kk = 0; kk < 2; ++kk) {
      const int slot = kk * 4 + lh;
      bf16x8 a[MF], b[NF];
#pragma unroll
      for (int mi = 0; mi < MF; ++mi)
        a[mi] = ldfrag(AsB, wr * (BM / 2) + mi * 16 + lr, slot);
#pragma unroll
      for (int ni = 0; ni < NF; ++ni)
        b[ni] = ldfrag(BsB, wc * (BN / 2) + ni * 16 + lr, slot);
      // ni OUTER so src0 (b[ni]) is constant across each inner 4-MFMA run
      // (R11: varying src0 per MFMA cost ~23%).
#pragma unroll
      for (int ni = 0; ni < NF; ++ni)
#pragma unroll
        for (int mi = 0; mi < MF; ++mi)
          acc[mi][ni] = __builtin_amdgcn_mfma_f32_16x16x32_bf16(b[ni], a[mi], acc[mi][ni], 0, 0, 0);
    }
    __syncthreads();
  }

  // Epilogue (C^T frags): m = ...+lr (fixed per thread/frag), n = ...+lh*4 + r.
  const float* be = bias + (size_t)e * N;
  u16* dst = (PHASE == 1) ? Hout : Yout;
#pragma unroll
  for (int mi = 0; mi < MF; ++mi) {
    int m = mt * BM + wr * (BM / 2) + mi * 16 + lr;
    if (m < cnt) {
      size_t orow = (size_t)(seg + m) * N;
#pragma unroll
      for (int ni = 0; ni < NF; ++ni) {
        int col = n0 + wc * (BN / 2) + ni * 16 + lh * 4;
        float4 bv = *(const float4*)(be + col);
        float v0 = acc[mi][ni][0] + bv.x;
        float v1 = acc[mi][ni][1] + bv.y;
        float v2 = acc[mi][ni][2] + bv.z;
        float v3 = acc[mi][ni][3] + bv.w;
        if (PHASE == 1) {
          v0 = fast_gelu(v0); v1 = fast_gelu(v1);
          v2 = fast_gelu(v2); v3 = fast_gelu(v3);
        }
        uint2 o;
        o.x = (unsigned)f2bf(v0) | ((unsigned)f2bf(v1) << 16);
        o.y = (unsigned)f2bf(v2) | ((unsigned)f2bf(v3) << 16);
        *(uint2*)(dst + orow + col) = o;
      }
    }
  }
}

// ---------------- combine: out[t] = w0*Y[inv0] + w1*Y[inv1] ----------------
__global__ void combine_kernel(const u16* __restrict__ Y, const int* __restrict__ inv,
                               const float* __restrict__ top_w, float* __restrict__ out) {
  int idx = blockIdx.x * 256 + threadIdx.x;   // TK*128 threads, 8 cols each
  int t = idx >> 7, c = (idx & 127) * 8;
  int s0 = inv[2 * t], s1 = inv[2 * t + 1];
  float w0 = top_w[2 * t], w1 = top_w[2 * t + 1];
  const uint4 y0 = *(const uint4*)(Y + (size_t)s0 * DDIM + c);
  const uint4 y1 = *(const uint4*)(Y + (size_t)s1 * DDIM + c);
  float4 o0, o1;
#define LO(u) __uint_as_float((u) << 16)
#define HI(u) __uint_as_float((u) & 0xffff0000u)
  o0.x = w0 * LO(y0.x) + w1 * LO(y1.x); o0.y = w0 * HI(y0.x) + w1 * HI(y1.x);
  o0.z = w0 * LO(y0.y) + w1 * LO(y1.y); o0.w = w0 * HI(y0.y) + w1 * HI(y1.y);
  o1.x = w0 * LO(y0.z) + w1 * LO(y1.z); o1.y = w0 * HI(y0.z) + w1 * HI(y1.z);
  o1.z = w0 * LO(y0.w) + w1 * LO(y1.w); o1.w = w0 * HI(y0.w) + w1 * HI(y1.w);
#undef LO
#undef HI
  float4* op = (float4*)(out + (size_t)t * DDIM + c);
  op[0] = o0; op[1] = o1;
}

extern "C" void kernel_launch(void* const* d_in, const int* in_sizes, int n_in,
                              void* d_out, int out_size, void* d_ws, size_t ws_size,
                              hipStream_t stream) {
  const float* x  = (const float*)d_in[0];
  const float* gw = (const float*)d_in[1];
  const float* gb = (const float*)d_in[2];
  const float* w1 = (const float*)d_in[3];
  const float* b1 = (const float*)d_in[4];
  const float* w2 = (const float*)d_in[5];
  const float* b2 = (const float*)d_in[6];
  float* out = (float*)d_out;

  char* ws = (char*)d_ws;
  int*   counts  = (int*)(ws + 0);
  int*   cursors = (int*)(ws + 64);
  int*   seg     = (int*)(ws + 128);
  int*   nt128   = (int*)(ws + 192);
  int*   map128  = (int*)(ws + 1024);
  int*   top_e   = (int*)(ws + 4096);
  float* top_w   = (float*)(ws + 4096 + 65536);
  int*   tok_ids = (int*)(ws + 4096 + 131072);
  float* tok_wt  = (float*)(ws + 4096 + 196608);
  int*   invm    = (int*)(ws + 4096 + 262144);
  // Xg and Y share [1MB, 36MB): Xg consumed by GEMM1, Y produced by GEMM2.
  u16*   Xg      = (u16*)(ws + ((size_t)1 << 20));    //  32 MB
  u16*   Y       = (u16*)(ws + ((size_t)1 << 20));    //  33.6 MB (same region)
  u16*   H       = (u16*)(ws + ((size_t)36 << 20));   // 128 MB
  u16*   wt      = (u16*)(ws + ((size_t)164 << 20));  //  64 MB (shared w1t/w2t)

  hipMemsetAsync(ws, 0, 256, stream);

  router_kernel<<<TK, 64, 0, stream>>>(x, gw, gb, top_e, top_w);
  count_kernel<<<TK / 256, 256, 0, stream>>>(top_e, counts);
  scan_kernel<<<1, 64, 0, stream>>>(counts, seg, cursors, nt128, map128);
  scatter_kernel<<<TK / 256, 256, 0, stream>>>(top_e, top_w, cursors, tok_ids, tok_wt, invm);
  gather_cast_kernel<<<2 * TK * 128 / 256, 256, 0, stream>>>(x, tok_ids, (uint4*)Xg);

  transpose_cast_kernel<<<dim3(DDIM / 64, FDIM / 64, NEXP), 256, 0, stream>>>(w1, wt, DDIM, FDIM);
  moe_gemm<1, 128, 128, 4, 4><<<dim3(MAXT128 * (FDIM / 128)), 256, 0, stream>>>(
      Xg, wt, b1, H, nullptr, seg, counts, nt128, map128, DDIM, FDIM);
  transpose_cast_kernel<<<dim3(FDIM / 64, DDIM / 64, NEXP), 256, 0, stream>>>(w2, wt, FDIM, DDIM);

  moe_gemm<3, 128, 128, 4, 4><<<dim3(MAXT128 * (DDIM / 128)), 256, 0, stream>>>(
      H, wt, b2, nullptr, Y, seg, counts, nt128, map128, FDIM, DDIM);
  combine_kernel<<<TK * 128 / 256, 256, 0, stream>>>(Y, invm, top_w, out);
}